// Round 4
// baseline (777.040 us; speedup 1.0000x reference)
//
#include <hip/hip_runtime.h>

// CapsuleLayer dynamic routing, fp32, MI355X.
// Never materialize u_hat [32,2048,32,32]=256MiB: recompute per routing pass
// from W (132 MB read/pass; HBM floor ~21us/pass). Logits reconstructed as
// dot(u_hat, v0[+v1]) so no b-state is stored.
// R3 counters: 1 block/CU (grid 256), Occ 20%, VALU 17% -> latency-bound.
// R4: IC=8 -> grid 512 (2 blocks/CU, same-XCD i-chunk pairing) + W register
// double-buffer prefetch. launch_bounds(512,4) caps VGPR at 128.

#define B_TOT 32
#define NI    2048
#define DIN   16
#define NO    32
#define DOUT  32
#define IC    8     // i-values per block
#define BH    16    // b-values per block (2 blocks cover the batch)

// ws layout (float offsets)
#define S0_OFF 0
#define S1_OFF 32768
#define S2_OFF 65536
#define V0_OFF 98304
#define VS_OFF 99328

__device__ __forceinline__ void fma2(float2& a, float s, float2 w) {
    a.x = fmaf(s, w.x, a.x);
    a.y = fmaf(s, w.y, a.y);
}

__device__ __forceinline__ void atom_add_f32(float* p, float v) {
#if defined(__HIP_DEVICE_COMPILE__)
    unsafeAtomicAdd(p, v);   // native global_atomic_add_f32 on gfx950
#else
    atomicAdd(p, v);
#endif
}

template <int PASS>
__global__ __launch_bounds__(512, 4)
void caps_pass(const float* __restrict__ U, const float* __restrict__ W,
               const float* __restrict__ Vprev, float* __restrict__ Sout)
{
    const int t  = threadIdx.x;
    const int j  = t >> 4;          // 0..31 output capsule
    const int dp = t & 15;          // d-pair: d = 2dp, 2dp+1
    // i-chunk = bid&255, b-half = bid>>8: the two blocks sharing an i-chunk
    // are 256 apart -> same XCD (256%8==0) -> W lines dedupe in L2.
    const int i0 = (blockIdx.x & 255) * IC;
    const int b0 = (blockIdx.x >> 8) * BH;

    __shared__ float lg[BH][NO];    // logits, then exp(logits)
    __shared__ float inv_sum[BH];

    float2 sacc[BH];
#pragma unroll
    for (int b = 0; b < BH; ++b) sacc[b] = make_float2(0.f, 0.f);

    // v to dot u_hat with (pass1: v0, pass2: v0+v1) — loop-invariant, hoisted.
    float2 vs[BH];
    if constexpr (PASS >= 1) {
#pragma unroll
        for (int b = 0; b < BH; ++b) {
            const float* vp = Vprev + ((b0 + b) * NO + j) * DOUT + 2 * dp;
            vs[b] = make_float2(vp[0], vp[1]);
        }
    }

    // W fragment loader: dst[c] = W[i, j, c, 2dp..2dp+1]
    auto load_w = [&](float2 (&dst)[DIN], int i) {
        const float* wp = W + ((size_t)(i * NO + j) * DIN) * DOUT + 2 * dp;
#pragma unroll
        for (int c = 0; c < DIN; ++c)
            dst[c] = *reinterpret_cast<const float2*>(wp + c * DOUT);
    };

    // compute body for one i using a ready W fragment
    auto body = [&](const float2 (&w2)[DIN], int i) {
        float2 uh[BH];
#pragma unroll
        for (int b = 0; b < BH; ++b) {
            // all lanes read the same 64B row of U -> L1 broadcast
            const float* up = U + ((size_t)((b0 + b) * NI + i)) * DIN;
            const float4 ua = *reinterpret_cast<const float4*>(up);
            const float4 ub = *reinterpret_cast<const float4*>(up + 4);
            const float4 uc = *reinterpret_cast<const float4*>(up + 8);
            const float4 ud = *reinterpret_cast<const float4*>(up + 12);
            float2 acc = make_float2(0.f, 0.f);
            fma2(acc, ua.x, w2[0]);  fma2(acc, ua.y, w2[1]);
            fma2(acc, ua.z, w2[2]);  fma2(acc, ua.w, w2[3]);
            fma2(acc, ub.x, w2[4]);  fma2(acc, ub.y, w2[5]);
            fma2(acc, ub.z, w2[6]);  fma2(acc, ub.w, w2[7]);
            fma2(acc, uc.x, w2[8]);  fma2(acc, uc.y, w2[9]);
            fma2(acc, uc.z, w2[10]); fma2(acc, uc.w, w2[11]);
            fma2(acc, ud.x, w2[12]); fma2(acc, ud.y, w2[13]);
            fma2(acc, ud.z, w2[14]); fma2(acc, ud.w, w2[15]);
            uh[b] = acc;

            if constexpr (PASS >= 1) {
                // logit partial: uh . v_prev  (this thread's 2 d's)
                float p = acc.x * vs[b].x + acc.y * vs[b].y;
                // sum over the 16 dp-lanes (same j)
                p += __shfl_xor(p, 1);
                p += __shfl_xor(p, 2);
                p += __shfl_xor(p, 4);
                p += __shfl_xor(p, 8);
                if (dp == 0) lg[b][j] = p;
            } else {
                // c is uniform 1/32: accumulate directly (scaled at the end)
                sacc[b].x += acc.x;
                sacc[b].y += acc.y;
            }
        }

        if constexpr (PASS >= 1) {
            __syncthreads();
            // softmax over j for each of the BH rows; thread t -> (row, jj)
            {
                const int row = t >> 5;   // 0..15
                const int jj  = t & 31;
                float e = __expf(lg[row][jj]);
                float s = e;
                s += __shfl_xor(s, 1);
                s += __shfl_xor(s, 2);
                s += __shfl_xor(s, 4);
                s += __shfl_xor(s, 8);
                s += __shfl_xor(s, 16);
                lg[row][jj] = e;          // own cell only: safe in-place
                if (jj == 0) inv_sum[row] = 1.0f / s;
            }
            __syncthreads();

#pragma unroll
            for (int b = 0; b < BH; ++b) {
                const float cc = lg[b][j] * inv_sum[b];
                sacc[b].x = fmaf(cc, uh[b].x, sacc[b].x);
                sacc[b].y = fmaf(cc, uh[b].y, sacc[b].y);
            }
            __syncthreads();  // lg reused next i
        }
    };

    // software-pipelined i-loop: two named W buffers (no runtime indexing),
    // next-i loads issued before current-i compute so HBM latency hides.
    float2 wA[DIN], wB[DIN];
    load_w(wA, i0);
    for (int ii = 0; ii < IC; ii += 2) {
        const int i = i0 + ii;
        load_w(wB, (ii + 1 < IC) ? i + 1 : i);
        body(wA, i);
        load_w(wA, (ii + 2 < IC) ? i + 2 : i);
        body(wB, i + 1);
    }

#pragma unroll
    for (int b = 0; b < BH; ++b) {
        float sx = sacc[b].x, sy = sacc[b].y;
        if constexpr (PASS == 0) { sx *= (1.0f / NO); sy *= (1.0f / NO); }
        float* sp = Sout + ((b0 + b) * NO + j) * DOUT + 2 * dp;
        atom_add_f32(sp,     sx);
        atom_add_f32(sp + 1, sy);
    }
}

// v = squash(s) [+ Vadd]; one thread per (b,j) row of 32 d's.
__global__ void caps_squash(const float* __restrict__ S,
                            const float* __restrict__ Vadd,
                            float* __restrict__ Out)
{
    const int cell = blockIdx.x * blockDim.x + threadIdx.x;  // b*32 + j
    if (cell >= B_TOT * NO) return;
    const float* sp = S + (size_t)cell * DOUT;
    float v[DOUT];
    float n2 = 0.f;
#pragma unroll
    for (int d = 0; d < DOUT; ++d) { v[d] = sp[d]; n2 = fmaf(v[d], v[d], n2); }
    const float scale = n2 / (1.0f + n2) / sqrtf(n2 + 1e-7f);
    float* op = Out + (size_t)cell * DOUT;
    if (Vadd != nullptr) {
        const float* vp = Vadd + (size_t)cell * DOUT;
#pragma unroll
        for (int d = 0; d < DOUT; ++d) op[d] = scale * v[d] + vp[d];
    } else {
#pragma unroll
        for (int d = 0; d < DOUT; ++d) op[d] = scale * v[d];
    }
}

extern "C" void kernel_launch(void* const* d_in, const int* in_sizes, int n_in,
                              void* d_out, int out_size, void* d_ws, size_t ws_size,
                              hipStream_t stream)
{
    const float* U = (const float*)d_in[0];   // [32, 2048, 16]
    const float* W = (const float*)d_in[1];   // [2048, 32, 16, 32]
    float* out = (float*)d_out;               // [32, 32, 32]
    float* ws  = (float*)d_ws;

    float* s0   = ws + S0_OFF;
    float* s1   = ws + S1_OFF;
    float* s2   = ws + S2_OFF;
    float* v0   = ws + V0_OFF;
    float* vsum = ws + VS_OFF;

    // zero the atomic s-accumulators (ws is poisoned 0xAA before every call)
    hipMemsetAsync(ws, 0, (size_t)3 * 32768 * sizeof(float), stream);

    const dim3 grid((NI / IC) * 2);   // 512 blocks: 2 per CU
    const dim3 blk(512);

    caps_pass<0><<<grid, blk, 0, stream>>>(U, W, nullptr, s0);
    caps_squash<<<8, 128, 0, stream>>>(s0, nullptr, v0);      // v0 = squash(s0)
    caps_pass<1><<<grid, blk, 0, stream>>>(U, W, v0, s1);
    caps_squash<<<8, 128, 0, stream>>>(s1, v0, vsum);         // vsum = v0 + squash(s1)
    caps_pass<2><<<grid, blk, 0, stream>>>(U, W, vsum, s2);
    caps_squash<<<8, 128, 0, stream>>>(s2, nullptr, out);     // out = squash(s2)
}

// Round 7
// 598.895 us; speedup vs baseline: 1.2975x; 1.2975x over previous
//
#include <hip/hip_runtime.h>

// CapsuleLayer dynamic routing, fp32, MI355X.
// Never materialize u_hat [32,2048,32,32]=256MiB: recompute per routing pass
// from W (132 MB read/pass; HBM floor ~21us/pass, fp32-VALU floor ~14us/pass).
// Logits reconstructed as dot(u_hat, v0[+v1]) so no b-state is stored.
// History: R3 (IC=16, grid 256, (512,1)): VGPR 84, no spill, but 1 block/CU ->
//   Occ 20%, VALU 17%, 159us/pass (latency-bound).
// R4 (pipeline + (512,4)): compiler capped VGPR at 64 -> massive scratch spill
//   (FETCH 470MB, WRITE 441MB) -> 263us/pass. REVERTED.
// R5 = R3 body exactly, IC=8 -> grid 512 = 2 blocks/CU, same-XCD i-chunk pairs.
// (R5/R6 benches were infra failures — same kernel, resubmitted.)

#define B_TOT 32
#define NI    2048
#define DIN   16
#define NO    32
#define DOUT  32
#define IC    8     // i-values per block
#define BH    16    // b-values per block (2 blocks cover the batch)

// ws layout (float offsets)
#define S0_OFF 0
#define S1_OFF 32768
#define S2_OFF 65536
#define V0_OFF 98304
#define VS_OFF 99328

__device__ __forceinline__ void fma2(float2& a, float s, float2 w) {
    a.x = fmaf(s, w.x, a.x);
    a.y = fmaf(s, w.y, a.y);
}

__device__ __forceinline__ void atom_add_f32(float* p, float v) {
#if defined(__HIP_DEVICE_COMPILE__)
    unsafeAtomicAdd(p, v);   // native global_atomic_add_f32 on gfx950
#else
    atomicAdd(p, v);
#endif
}

template <int PASS>
__global__ __launch_bounds__(512, 1)
void caps_pass(const float* __restrict__ U, const float* __restrict__ W,
               const float* __restrict__ Vprev, float* __restrict__ Sout)
{
    const int t  = threadIdx.x;
    const int j  = t >> 4;          // 0..31 output capsule
    const int dp = t & 15;          // d-pair: d = 2dp, 2dp+1
    // i-chunk = bid&255, b-half = bid>>8: the two blocks sharing an i-chunk
    // are 256 apart -> 256%8==0 -> same XCD -> W lines dedupe in that L2.
    const int i0 = (blockIdx.x & 255) * IC;
    const int b0 = (blockIdx.x >> 8) * BH;

    __shared__ float lg[BH][NO];    // logits, then exp(logits)
    __shared__ float inv_sum[BH];

    float2 sacc[BH];
#pragma unroll
    for (int b = 0; b < BH; ++b) sacc[b] = make_float2(0.f, 0.f);

    // v to dot u_hat with (pass1: v0, pass2: v0+v1) — loop-invariant, hoisted.
    float2 vs[BH];
    if constexpr (PASS >= 1) {
#pragma unroll
        for (int b = 0; b < BH; ++b) {
            const float* vp = Vprev + ((b0 + b) * NO + j) * DOUT + 2 * dp;
            vs[b] = make_float2(vp[0], vp[1]);
        }
    }

    for (int ii = 0; ii < IC; ++ii) {
        const int i = i0 + ii;

        // W fragment for this thread: w2[c] = W[i, j, c, 2dp..2dp+1]
        float2 w2[DIN];
        const float* wp = W + ((size_t)(i * NO + j) * DIN) * DOUT + 2 * dp;
#pragma unroll
        for (int c = 0; c < DIN; ++c)
            w2[c] = *reinterpret_cast<const float2*>(wp + c * DOUT);

        float2 uh[BH];
#pragma unroll
        for (int b = 0; b < BH; ++b) {
            // all lanes read the same 64B row of U -> cache-line broadcast
            const float* up = U + ((size_t)((b0 + b) * NI + i)) * DIN;
            const float4 ua = *reinterpret_cast<const float4*>(up);
            const float4 ub = *reinterpret_cast<const float4*>(up + 4);
            const float4 uc = *reinterpret_cast<const float4*>(up + 8);
            const float4 ud = *reinterpret_cast<const float4*>(up + 12);
            float2 acc = make_float2(0.f, 0.f);
            fma2(acc, ua.x, w2[0]);  fma2(acc, ua.y, w2[1]);
            fma2(acc, ua.z, w2[2]);  fma2(acc, ua.w, w2[3]);
            fma2(acc, ub.x, w2[4]);  fma2(acc, ub.y, w2[5]);
            fma2(acc, ub.z, w2[6]);  fma2(acc, ub.w, w2[7]);
            fma2(acc, uc.x, w2[8]);  fma2(acc, uc.y, w2[9]);
            fma2(acc, uc.z, w2[10]); fma2(acc, uc.w, w2[11]);
            fma2(acc, ud.x, w2[12]); fma2(acc, ud.y, w2[13]);
            fma2(acc, ud.z, w2[14]); fma2(acc, ud.w, w2[15]);
            uh[b] = acc;

            if constexpr (PASS >= 1) {
                // logit partial: uh . v_prev  (this thread's 2 d's)
                float p = acc.x * vs[b].x + acc.y * vs[b].y;
                // sum over the 16 dp-lanes (same j)
                p += __shfl_xor(p, 1);
                p += __shfl_xor(p, 2);
                p += __shfl_xor(p, 4);
                p += __shfl_xor(p, 8);
                if (dp == 0) lg[b][j] = p;
            } else {
                // c is uniform 1/32: accumulate directly (scaled at the end)
                sacc[b].x += acc.x;
                sacc[b].y += acc.y;
            }
        }

        if constexpr (PASS >= 1) {
            __syncthreads();
            // softmax over j for each of the BH rows; thread t -> (row, jj)
            {
                const int row = t >> 5;   // 0..15
                const int jj  = t & 31;
                float e = __expf(lg[row][jj]);
                float s = e;
                s += __shfl_xor(s, 1);
                s += __shfl_xor(s, 2);
                s += __shfl_xor(s, 4);
                s += __shfl_xor(s, 8);
                s += __shfl_xor(s, 16);
                lg[row][jj] = e;          // own cell only: safe in-place
                if (jj == 0) inv_sum[row] = 1.0f / s;
            }
            __syncthreads();

#pragma unroll
            for (int b = 0; b < BH; ++b) {
                const float cc = lg[b][j] * inv_sum[b];
                sacc[b].x = fmaf(cc, uh[b].x, sacc[b].x);
                sacc[b].y = fmaf(cc, uh[b].y, sacc[b].y);
            }
            __syncthreads();  // lg reused next i
        }
    }

#pragma unroll
    for (int b = 0; b < BH; ++b) {
        float sx = sacc[b].x, sy = sacc[b].y;
        if constexpr (PASS == 0) { sx *= (1.0f / NO); sy *= (1.0f / NO); }
        float* sp = Sout + ((b0 + b) * NO + j) * DOUT + 2 * dp;
        atom_add_f32(sp,     sx);
        atom_add_f32(sp + 1, sy);
    }
}

// v = squash(s) [+ Vadd]; one thread per (b,j) row of 32 d's.
__global__ void caps_squash(const float* __restrict__ S,
                            const float* __restrict__ Vadd,
                            float* __restrict__ Out)
{
    const int cell = blockIdx.x * blockDim.x + threadIdx.x;  // b*32 + j
    if (cell >= B_TOT * NO) return;
    const float* sp = S + (size_t)cell * DOUT;
    float v[DOUT];
    float n2 = 0.f;
#pragma unroll
    for (int d = 0; d < DOUT; ++d) { v[d] = sp[d]; n2 = fmaf(v[d], v[d], n2); }
    const float scale = n2 / (1.0f + n2) / sqrtf(n2 + 1e-7f);
    float* op = Out + (size_t)cell * DOUT;
    if (Vadd != nullptr) {
        const float* vp = Vadd + (size_t)cell * DOUT;
#pragma unroll
        for (int d = 0; d < DOUT; ++d) op[d] = scale * v[d] + vp[d];
    } else {
#pragma unroll
        for (int d = 0; d < DOUT; ++d) op[d] = scale * v[d];
    }
}

extern "C" void kernel_launch(void* const* d_in, const int* in_sizes, int n_in,
                              void* d_out, int out_size, void* d_ws, size_t ws_size,
                              hipStream_t stream)
{
    const float* U = (const float*)d_in[0];   // [32, 2048, 16]
    const float* W = (const float*)d_in[1];   // [2048, 32, 16, 32]
    float* out = (float*)d_out;               // [32, 32, 32]
    float* ws  = (float*)d_ws;

    float* s0   = ws + S0_OFF;
    float* s1   = ws + S1_OFF;
    float* s2   = ws + S2_OFF;
    float* v0   = ws + V0_OFF;
    float* vsum = ws + VS_OFF;

    // zero the atomic s-accumulators (ws is poisoned 0xAA before every call)
    hipMemsetAsync(ws, 0, (size_t)3 * 32768 * sizeof(float), stream);

    const dim3 grid((NI / IC) * 2);   // 512 blocks: 2 per CU
    const dim3 blk(512);

    caps_pass<0><<<grid, blk, 0, stream>>>(U, W, nullptr, s0);
    caps_squash<<<8, 128, 0, stream>>>(s0, nullptr, v0);      // v0 = squash(s0)
    caps_pass<1><<<grid, blk, 0, stream>>>(U, W, v0, s1);
    caps_squash<<<8, 128, 0, stream>>>(s1, v0, vsum);         // vsum = v0 + squash(s1)
    caps_pass<2><<<grid, blk, 0, stream>>>(U, W, vsum, s2);
    caps_squash<<<8, 128, 0, stream>>>(s2, nullptr, out);     // out = squash(s2)
}

// Round 13
// 565.486 us; speedup vs baseline: 1.3741x; 1.0591x over previous
//
#include <hip/hip_runtime.h>

// CapsuleLayer dynamic routing, fp32, MI355X.
// Never materialize u_hat [32,2048,32,32]=256MiB: recompute per routing pass
// from W (132 MB read/pass; HBM floor ~21us/pass, fp32-VALU floor ~14us/pass).
// Logits reconstructed as dot(u_hat, v0[+v1]) so no b-state is stored.
// History:
//  R3 (grid 256, (512,1)): VGPR 84, no spill, Occ 20%, VALU 17%, 159us/pass.
//  R4 ((512,4) pipeline): VGPR capped 64 -> spill storm -> 263us/pass. REVERTED.
//  R7 (grid 512, 2 blk/CU): Occ/VALU unchanged -> VMEM-issue-bound theory:
//      64 of 80 VMEM instr/wave/i are per-lane U broadcast loads.
//  R8/R11: stage U slice (8KB) in LDS; body reads via uniform ds_read_b128.
//      R11 FAILED correctness: WS overlap bug — vsum (VS_OFF 99328) overlapped
//      v0 (needs 32768 floats from 98304) -> read/write race in caps_squash
//      (latent since R0; R3/R7 passed on lucky scheduling).
//  R12 = R8 body unchanged + VS_OFF 131072 (disjoint buffers).
//  (R12 bench was an infra failure — same kernel, resubmitted.)

#define B_TOT 32
#define NI    2048
#define DIN   16
#define NO    32
#define DOUT  32
#define IC    8     // i-values per block
#define BH    16    // b-values per block (2 blocks cover the batch)

// ws layout (float offsets): s0,s1,s2,v0,vsum each 32768 floats (640KB total)
#define S0_OFF 0
#define S1_OFF 32768
#define S2_OFF 65536
#define V0_OFF 98304
#define VS_OFF 131072

__device__ __forceinline__ void fma2(float2& a, float s, float2 w) {
    a.x = fmaf(s, w.x, a.x);
    a.y = fmaf(s, w.y, a.y);
}

__device__ __forceinline__ void atom_add_f32(float* p, float v) {
#if defined(__HIP_DEVICE_COMPILE__)
    unsafeAtomicAdd(p, v);   // native global_atomic_add_f32 on gfx950
#else
    atomicAdd(p, v);
#endif
}

template <int PASS>
__global__ __launch_bounds__(512, 1)
void caps_pass(const float* __restrict__ U, const float* __restrict__ W,
               const float* __restrict__ Vprev, float* __restrict__ Sout)
{
    const int t  = threadIdx.x;
    const int j  = t >> 4;          // 0..31 output capsule
    const int dp = t & 15;          // d-pair: d = 2dp, 2dp+1
    // i-chunk = bid&255, b-half = bid>>8: the two blocks sharing an i-chunk
    // are 256 apart -> 256%8==0 -> same XCD -> W lines dedupe in that L2.
    const int i0 = (blockIdx.x & 255) * IC;
    const int b0 = (blockIdx.x >> 8) * BH;

    __shared__ float lg[BH][NO];    // logits, then exp(logits)
    __shared__ float inv_sum[BH];
    // U slice for this block: [b][ii*16+c] = [16][128] floats = 8 KB.
    __shared__ __align__(16) float Ulds[BH * IC * DIN];

    // ---- stage U once: 1 coalesced float4 load + 1 linear ds_write per thread.
    // thread t -> b = t>>5, idx = t&31; 128 contiguous floats per b row
    // (i=i0..i0+7, c=0..15); LDS byte addr = t*16 (conflict-free).
    {
        const int b   = t >> 5;
        const int idx = t & 31;
        const float4 u4 = *reinterpret_cast<const float4*>(
            U + ((size_t)(b0 + b) * NI + i0) * DIN + idx * 4);
        *reinterpret_cast<float4*>(&Ulds[t * 4]) = u4;
    }
    __syncthreads();

    float2 sacc[BH];
#pragma unroll
    for (int b = 0; b < BH; ++b) sacc[b] = make_float2(0.f, 0.f);

    // v to dot u_hat with (pass1: v0, pass2: v0+v1) — loop-invariant, hoisted.
    float2 vs[BH];
    if constexpr (PASS >= 1) {
#pragma unroll
        for (int b = 0; b < BH; ++b) {
            const float* vp = Vprev + ((b0 + b) * NO + j) * DOUT + 2 * dp;
            vs[b] = make_float2(vp[0], vp[1]);
        }
    }

    for (int ii = 0; ii < IC; ++ii) {
        const int i = i0 + ii;

        // W fragment for this thread: w2[c] = W[i, j, c, 2dp..2dp+1]
        float2 w2[DIN];
        const float* wp = W + ((size_t)(i * NO + j) * DIN) * DOUT + 2 * dp;
#pragma unroll
        for (int c = 0; c < DIN; ++c)
            w2[c] = *reinterpret_cast<const float2*>(wp + c * DOUT);

        float2 uh[BH];
#pragma unroll
        for (int b = 0; b < BH; ++b) {
            // uniform-address LDS reads -> broadcast, no VMEM, no conflicts
            const float* ub_ptr = &Ulds[(b * IC + ii) * DIN];
            const float4 ua = *reinterpret_cast<const float4*>(ub_ptr);
            const float4 ubv = *reinterpret_cast<const float4*>(ub_ptr + 4);
            const float4 uc = *reinterpret_cast<const float4*>(ub_ptr + 8);
            const float4 ud = *reinterpret_cast<const float4*>(ub_ptr + 12);
            float2 acc = make_float2(0.f, 0.f);
            fma2(acc, ua.x, w2[0]);  fma2(acc, ua.y, w2[1]);
            fma2(acc, ua.z, w2[2]);  fma2(acc, ua.w, w2[3]);
            fma2(acc, ubv.x, w2[4]); fma2(acc, ubv.y, w2[5]);
            fma2(acc, ubv.z, w2[6]); fma2(acc, ubv.w, w2[7]);
            fma2(acc, uc.x, w2[8]);  fma2(acc, uc.y, w2[9]);
            fma2(acc, uc.z, w2[10]); fma2(acc, uc.w, w2[11]);
            fma2(acc, ud.x, w2[12]); fma2(acc, ud.y, w2[13]);
            fma2(acc, ud.z, w2[14]); fma2(acc, ud.w, w2[15]);
            uh[b] = acc;

            if constexpr (PASS >= 1) {
                // logit partial: uh . v_prev  (this thread's 2 d's)
                float p = acc.x * vs[b].x + acc.y * vs[b].y;
                // sum over the 16 dp-lanes (same j)
                p += __shfl_xor(p, 1);
                p += __shfl_xor(p, 2);
                p += __shfl_xor(p, 4);
                p += __shfl_xor(p, 8);
                if (dp == 0) lg[b][j] = p;
            } else {
                // c is uniform 1/32: accumulate directly (scaled at the end)
                sacc[b].x += acc.x;
                sacc[b].y += acc.y;
            }
        }

        if constexpr (PASS >= 1) {
            __syncthreads();
            // softmax over j for each of the BH rows; thread t -> (row, jj)
            {
                const int row = t >> 5;   // 0..15
                const int jj  = t & 31;
                float e = __expf(lg[row][jj]);
                float s = e;
                s += __shfl_xor(s, 1);
                s += __shfl_xor(s, 2);
                s += __shfl_xor(s, 4);
                s += __shfl_xor(s, 8);
                s += __shfl_xor(s, 16);
                lg[row][jj] = e;          // own cell only: safe in-place
                if (jj == 0) inv_sum[row] = 1.0f / s;
            }
            __syncthreads();

#pragma unroll
            for (int b = 0; b < BH; ++b) {
                const float cc = lg[b][j] * inv_sum[b];
                sacc[b].x = fmaf(cc, uh[b].x, sacc[b].x);
                sacc[b].y = fmaf(cc, uh[b].y, sacc[b].y);
            }
            __syncthreads();  // lg reused next i
        }
    }

#pragma unroll
    for (int b = 0; b < BH; ++b) {
        float sx = sacc[b].x, sy = sacc[b].y;
        if constexpr (PASS == 0) { sx *= (1.0f / NO); sy *= (1.0f / NO); }
        float* sp = Sout + ((b0 + b) * NO + j) * DOUT + 2 * dp;
        atom_add_f32(sp,     sx);
        atom_add_f32(sp + 1, sy);
    }
}

// v = squash(s) [+ Vadd]; one thread per (b,j) row of 32 d's.
__global__ void caps_squash(const float* __restrict__ S,
                            const float* __restrict__ Vadd,
                            float* __restrict__ Out)
{
    const int cell = blockIdx.x * blockDim.x + threadIdx.x;  // b*32 + j
    if (cell >= B_TOT * NO) return;
    const float* sp = S + (size_t)cell * DOUT;
    float v[DOUT];
    float n2 = 0.f;
#pragma unroll
    for (int d = 0; d < DOUT; ++d) { v[d] = sp[d]; n2 = fmaf(v[d], v[d], n2); }
    const float scale = n2 / (1.0f + n2) / sqrtf(n2 + 1e-7f);
    float* op = Out + (size_t)cell * DOUT;
    if (Vadd != nullptr) {
        const float* vp = Vadd + (size_t)cell * DOUT;
#pragma unroll
        for (int d = 0; d < DOUT; ++d) op[d] = scale * v[d] + vp[d];
    } else {
#pragma unroll
        for (int d = 0; d < DOUT; ++d) op[d] = scale * v[d];
    }
}

extern "C" void kernel_launch(void* const* d_in, const int* in_sizes, int n_in,
                              void* d_out, int out_size, void* d_ws, size_t ws_size,
                              hipStream_t stream)
{
    const float* U = (const float*)d_in[0];   // [32, 2048, 16]
    const float* W = (const float*)d_in[1];   // [2048, 32, 16, 32]
    float* out = (float*)d_out;               // [32, 32, 32]
    float* ws  = (float*)d_ws;

    float* s0   = ws + S0_OFF;
    float* s1   = ws + S1_OFF;
    float* s2   = ws + S2_OFF;
    float* v0   = ws + V0_OFF;
    float* vsum = ws + VS_OFF;

    // zero the atomic s-accumulators (ws is poisoned 0xAA before every call)
    hipMemsetAsync(ws, 0, (size_t)3 * 32768 * sizeof(float), stream);

    const dim3 grid((NI / IC) * 2);   // 512 blocks: 2 per CU
    const dim3 blk(512);

    caps_pass<0><<<grid, blk, 0, stream>>>(U, W, nullptr, s0);
    caps_squash<<<8, 128, 0, stream>>>(s0, nullptr, v0);      // v0 = squash(s0)
    caps_pass<1><<<grid, blk, 0, stream>>>(U, W, v0, s1);
    caps_squash<<<8, 128, 0, stream>>>(s1, v0, vsum);         // vsum = v0 + squash(s1)
    caps_pass<2><<<grid, blk, 0, stream>>>(U, W, vsum, s2);
    caps_squash<<<8, 128, 0, stream>>>(s2, nullptr, out);     // out = squash(s2)
}